// Round 1
// baseline (1959.902 us; speedup 1.0000x reference)
//
#include <hip/hip_runtime.h>
#include <hip/hip_bf16.h>
#include <stdint.h>

#define NN 20000      // nodes
#define NE 640000     // edges
#define NF 128        // input features
#define NH 256        // hidden
#define NT 32         // time scales
#define NG 128        // graphs
#define DMAX 12       // truncated Chebyshev degree: |coefs[:,d>12]| < 1e-7 (heat kernel Bessel decay)
#define NTERMS (DMAX + 1)
#define NSLICES 31    // acc slices consumed (t'=28 is dropped by VALID pool, so slice 31 unused)
#define TPOOL 14
#define FDIM (TPOOL * NH)          // 3584
#define SLICE ((size_t)NN * NF)    // 2,560,000 elements per time slice

typedef float f32x4 __attribute__((ext_vector_type(4)));
typedef short bf16x8 __attribute__((ext_vector_type(8)));

__device__ __forceinline__ unsigned short f2bf(float f) {
  unsigned u = __float_as_uint(f);
  return (unsigned short)((u + 0x7fffu + ((u >> 16) & 1u)) >> 16);  // RNE
}
__device__ __forceinline__ float bf2f(unsigned short h) {
  return __uint_as_float(((unsigned)h) << 16);
}
__device__ __forceinline__ unsigned pack2(float a, float b) {
  return (unsigned)f2bf(a) | ((unsigned)f2bf(b) << 16);
}

// ---------------- CSR build ----------------
__global__ void k_hist_edges(const int* __restrict__ ei, int* __restrict__ offs) {
  const int e = blockIdx.x * 256 + threadIdx.x;  // grid is exact
  atomicAdd(&offs[ei[NE + e] + 1], 1);
}

__global__ void k_hist_batch(const int* __restrict__ batch, int* __restrict__ gcnt) {
  const int n = blockIdx.x * 256 + threadIdx.x;
  if (n < NN) atomicAdd(&gcnt[batch[n]], 1);
}

__global__ __launch_bounds__(1024) void k_scan(int* __restrict__ offs, int* __restrict__ cursor) {
  __shared__ int s[1024];
  const int tid = threadIdx.x;
  int loc[20];
  int run = 0;
#pragma unroll
  for (int k = 0; k < 20; ++k) {
    const int i = tid * 20 + k;
    const int v = (i <= NN) ? offs[i] : 0;
    run += v;
    loc[k] = run;
  }
  s[tid] = run;
  __syncthreads();
  for (int off = 1; off < 1024; off <<= 1) {
    const int add = (tid >= off) ? s[tid - off] : 0;
    __syncthreads();
    s[tid] += add;
    __syncthreads();
  }
  const int pre = (tid > 0) ? s[tid - 1] : 0;
#pragma unroll
  for (int k = 0; k < 20; ++k) {
    const int i = tid * 20 + k;
    if (i <= NN) {
      const int val = pre + loc[k];
      offs[i] = val;
      if (i < NN) cursor[i] = val;
    }
  }
}

__global__ void k_fill(const int* __restrict__ ei, const float* __restrict__ ew,
                       int* __restrict__ cursor, int* __restrict__ csr_src,
                       float* __restrict__ csr_w) {
  const int e = blockIdx.x * 256 + threadIdx.x;  // exact grid
  const int src = ei[e];
  const int dst = ei[NE + e];
  const int p = atomicAdd(&cursor[dst], 1);
  csr_src[p] = src;
  csr_w[p] = ew[e];
}

// ---------------- repack conv weights into MFMA-B fragment order ----------------
// btp[((kk*256 + o)*4 + g)*8 + j] = conv_w[o][f][kc], K-index = kc*128 + kq*32 + g*8 + j,
// kk = kc*4 + kq.  A wave's 16B-per-lane B-frag load is then fully contiguous (1 KB/wave).
__global__ void k_prep(const float* __restrict__ conv_w, unsigned short* __restrict__ btp) {
  const int idx = blockIdx.x * 256 + threadIdx.x;  // 131072 exact
  const int j = idx & 7;
  const int g = (idx >> 3) & 3;
  const int o = (idx >> 5) & 255;
  const int kk = idx >> 13;
  const int kc = kk >> 2, kq = kk & 3;
  const int f = kq * 32 + g * 8 + j;
  btp[idx] = f2bf(conv_w[((size_t)o * NF + f) * 4 + kc]);
}

// ---------------- Chebyshev recursion step: vout = (first ? A*vin : 2*A*vin - sub) ----------------
// thread = (node n, float4 feature chunk c).  32 lanes of a node gather a contiguous 512B row.
__global__ __launch_bounds__(256) void k_spmv(
    const float* __restrict__ vin, const float* __restrict__ sub,
    float* __restrict__ vout, unsigned short* __restrict__ tslice,
    const int* __restrict__ offs, const int* __restrict__ csr_src,
    const float* __restrict__ csr_w, int first) {
  const int id = blockIdx.x * 256 + threadIdx.x;  // exact 640000
  const int n = id >> 5;
  const int c = id & 31;
  const int jb = offs[n], je = offs[n + 1];
  const f32x4* vi = (const f32x4*)vin;
  f32x4 acc = (f32x4)0.f;
  for (int j = jb; j < je; ++j) {
    const int s = csr_src[j];
    const float wgt = csr_w[j];
    acc += wgt * vi[(size_t)s * 32 + c];
  }
  f32x4 res;
  if (first) {
    res = acc;
  } else {
    const f32x4 t2 = ((const f32x4*)sub)[(size_t)n * 32 + c];  // sub may alias vout (safe: own elem)
    res = 2.f * acc - t2;
  }
  ((f32x4*)vout)[(size_t)n * 32 + c] = res;
  uint2 u;
  u.x = pack2(res.x, res.y);
  u.y = pack2(res.z, res.w);
  ((uint2*)tslice)[(size_t)n * 32 + c] = u;
}

// ---------------- acc[t][n][f] = sum_d coefs[t][d] * T_d[n][f]  (bf16 out) ----------------
__global__ __launch_bounds__(256) void k_acc(
    const float* __restrict__ x, const unsigned short* __restrict__ tstore,
    const float* __restrict__ coefs, unsigned short* __restrict__ accb) {
  __shared__ float sc[NT * NTERMS];
  const int tid = threadIdx.x;
  for (int i = tid; i < NT * NTERMS; i += 256) {
    const int t = i / NTERMS, d = i % NTERMS;
    sc[i] = coefs[t * 101 + d];
  }
  __syncthreads();
  const size_t id = (size_t)blockIdx.x * 256 + tid;
  const int n = (int)(id >> 6);
  const int fp = (int)(id & 63);  // feature pair
  if (n >= NN) return;
  float va[NTERMS], vb[NTERMS];
  va[0] = x[(size_t)n * NF + 2 * fp];
  vb[0] = x[(size_t)n * NF + 2 * fp + 1];
  const unsigned* ts = (const unsigned*)tstore;
#pragma unroll
  for (int d = 1; d <= DMAX; ++d) {
    const unsigned u = ts[(size_t)(d - 1) * (SLICE / 2) + (size_t)n * 64 + fp];
    va[d] = bf2f((unsigned short)(u & 0xffff));
    vb[d] = bf2f((unsigned short)(u >> 16));
  }
  unsigned* ab = (unsigned*)accb;
#pragma unroll
  for (int t = 0; t < NSLICES; ++t) {
    float sa = 0.f, sb = 0.f;
#pragma unroll
    for (int d = 0; d < NTERMS; ++d) {
      sa += sc[t * NTERMS + d] * va[d];
      sb += sc[t * NTERMS + d] * vb[d];
    }
    ab[(size_t)t * (SLICE / 2) + (size_t)n * 64 + fp] = pack2(sa, sb);
  }
}

// ---------------- fused conv(K=4) + bias + maxpool(2) + relu + per-graph segment sum ----------------
// block = 64 nodes, 4 waves; wave w owns output channels [64w, 64w+64).
// GEMM per t': (64 nodes x 512) @ (512 x 256) via mfma_f32_16x16x32_bf16,
// K-dim = (kc,f), A = acc slices t'+kc, B = btp.
__global__ __launch_bounds__(256, 2) void k_conv(
    const unsigned short* __restrict__ accb, const unsigned short* __restrict__ btp,
    const float* __restrict__ conv_b, const int* __restrict__ batch,
    float* __restrict__ gsums) {
  __shared__ float gsl[2 * FDIM];  // per-block partial sums for 2 local graphs
  __shared__ int batch_loc[64];
  __shared__ int sgb;
  const int tid = threadIdx.x;
  const int n0 = blockIdx.x * 64;
  const int w = tid >> 6;
  const int l = tid & 63;
  const int lr = l & 15;
  const int lg = l >> 4;

  for (int i = tid; i < 2 * FDIM; i += 256) gsl[i] = 0.f;
  if (tid < 64) batch_loc[tid] = batch[(n0 + tid) < NN ? (n0 + tid) : (NN - 1)];
  if (tid == 0) sgb = batch[n0 < NN ? n0 : NN - 1];
  __syncthreads();
  const int gbase = sgb;

  float bias[4];
#pragma unroll
  for (int nf = 0; nf < 4; ++nf) bias[nf] = conv_b[w * 64 + nf * 16 + lr];

  int arow[4];
#pragma unroll
  for (int m = 0; m < 4; ++m) {
    const int r = n0 + m * 16 + lr;
    arow[m] = r < NN ? r : NN - 1;  // clamp pad rows (contributions skipped below)
  }

  f32x4 pend[4][4];

  for (int tp2 = 0; tp2 < 28; ++tp2) {  // t' = 0..27 (t'=28 dropped by pool)
    f32x4 hacc[4][4];
#pragma unroll
    for (int m = 0; m < 4; ++m)
#pragma unroll
      for (int nf = 0; nf < 4; ++nf) hacc[m][nf] = (f32x4)0.f;

#pragma unroll
    for (int kk = 0; kk < 16; ++kk) {
      const int kc = kk >> 2, kq = kk & 3;
      bf16x8 a[4], b[4];
      const unsigned short* abase =
          accb + (size_t)(tp2 + kc) * SLICE + (size_t)(kq * 32 + lg * 8);
#pragma unroll
      for (int m = 0; m < 4; ++m) a[m] = *(const bf16x8*)(abase + (size_t)arow[m] * NF);
      const unsigned short* bbase = btp + ((size_t)kk * 256 + w * 64 + lr) * 32 + lg * 8;
#pragma unroll
      for (int nf = 0; nf < 4; ++nf) b[nf] = *(const bf16x8*)(bbase + nf * 512);
#pragma unroll
      for (int m = 0; m < 4; ++m)
#pragma unroll
        for (int nf = 0; nf < 4; ++nf)
          hacc[m][nf] = __builtin_amdgcn_mfma_f32_16x16x32_bf16(a[m], b[nf], hacc[m][nf], 0, 0, 0);
    }
#pragma unroll
    for (int m = 0; m < 4; ++m)
#pragma unroll
      for (int nf = 0; nf < 4; ++nf) hacc[m][nf] += bias[nf];

    if ((tp2 & 1) == 0) {
#pragma unroll
      for (int m = 0; m < 4; ++m)
#pragma unroll
        for (int nf = 0; nf < 4; ++nf) pend[m][nf] = hacc[m][nf];
    } else {
      const int tp = tp2 >> 1;
#pragma unroll
      for (int m = 0; m < 4; ++m) {
#pragma unroll
        for (int r = 0; r < 4; ++r) {
          const int nloc = m * 16 + lg * 4 + r;  // D-frag row = (lane>>4)*4 + reg
          const int n = n0 + nloc;
          if (n < NN) {
            const int gi = batch_loc[nloc] - gbase;
#pragma unroll
            for (int nf = 0; nf < 4; ++nf) {
              const float v = fmaxf(fmaxf(pend[m][nf][r], hacc[m][nf][r]), 0.f);
              const int idx = tp * 256 + w * 64 + nf * 16 + lr;  // D-frag col = lane&15
              if (gi < 2) atomicAdd(&gsl[gi * FDIM + idx], v);
              else atomicAdd(&gsums[(size_t)(gbase + gi) * FDIM + idx], v);
            }
          }
        }
      }
    }
  }
  __syncthreads();
  for (int i = tid; i < 2 * FDIM; i += 256) {
    const int gi = i / FDIM;
    const int g = gbase + gi;
    const float v = gsl[i];
    if (g < NG && v != 0.f) atomicAdd(&gsums[(size_t)g * FDIM + (i - gi * FDIM)], v);
  }
}

// ---------------- mean, relu, FC, log_softmax ----------------
__global__ __launch_bounds__(256) void k_final(
    const float* __restrict__ gsums, const int* __restrict__ gcnt,
    const float* __restrict__ fc_w, const float* __restrict__ fc_b,
    float* __restrict__ out) {
  __shared__ float z[FDIM];
  __shared__ float red[10][4];
  __shared__ float slog[10];
  const int g = blockIdx.x;
  const int tid = threadIdx.x;
  const float cnt = fmaxf((float)gcnt[g], 1.f);
  for (int i = tid; i < FDIM; i += 256) z[i] = fmaxf(gsums[(size_t)g * FDIM + i] / cnt, 0.f);
  __syncthreads();
  for (int j = 0; j < 10; ++j) {
    float p = 0.f;
    for (int i = tid; i < FDIM; i += 256) p += z[i] * fc_w[(size_t)j * FDIM + i];
    for (int off = 32; off >= 1; off >>= 1) p += __shfl_down(p, off, 64);
    if ((tid & 63) == 0) red[j][tid >> 6] = p;
  }
  __syncthreads();
  if (tid < 10) slog[tid] = red[tid][0] + red[tid][1] + red[tid][2] + red[tid][3] + fc_b[tid];
  __syncthreads();
  if (tid == 0) {
    float m = slog[0];
    for (int j = 1; j < 10; ++j) m = fmaxf(m, slog[j]);
    float se = 0.f;
    for (int j = 0; j < 10; ++j) se += expf(slog[j] - m);
    const float lse = m + logf(se);
    for (int j = 0; j < 10; ++j) out[g * 10 + j] = slog[j] - lse;
  }
}

extern "C" void kernel_launch(void* const* d_in, const int* in_sizes, int n_in,
                              void* d_out, int out_size, void* d_ws, size_t ws_size,
                              hipStream_t stream) {
  const float* x      = (const float*)d_in[0];
  const int*   ei     = (const int*)d_in[1];
  const float* ew     = (const float*)d_in[2];
  const int*   batch  = (const int*)d_in[3];
  const float* coefs  = (const float*)d_in[4];
  const float* conv_w = (const float*)d_in[5];
  const float* conv_b = (const float*)d_in[6];
  const float* fc_w   = (const float*)d_in[7];
  const float* fc_b   = (const float*)d_in[8];
  float* out = (float*)d_out;
  (void)in_sizes; (void)n_in; (void)out_size; (void)ws_size;

  size_t off = 0;
  auto alloc = [&](size_t bytes) -> void* {
    void* p = (char*)d_ws + off;
    off += (bytes + 255) & ~(size_t)255;
    return p;
  };
  int* offs              = (int*)alloc((NN + 1) * 4);
  int* cursor            = (int*)alloc((size_t)NN * 4);
  int* csr_src           = (int*)alloc((size_t)NE * 4);
  float* csr_w           = (float*)alloc((size_t)NE * 4);
  int* gcnt              = (int*)alloc(NG * 4);
  float* gsums           = (float*)alloc((size_t)NG * FDIM * 4);
  float* rotA            = (float*)alloc(SLICE * 4);
  float* rotB            = (float*)alloc(SLICE * 4);
  unsigned short* tstore = (unsigned short*)alloc((size_t)DMAX * SLICE * 2);
  unsigned short* accb   = (unsigned short*)alloc((size_t)NSLICES * SLICE * 2);
  unsigned short* btp    = (unsigned short*)alloc((size_t)16 * 256 * 32 * 2);
  // total ~249 MB

  hipMemsetAsync(offs, 0, (NN + 1) * 4, stream);
  hipMemsetAsync(gcnt, 0, NG * 4, stream);
  hipMemsetAsync(gsums, 0, (size_t)NG * FDIM * 4, stream);

  k_hist_edges<<<NE / 256, 256, 0, stream>>>(ei, offs);
  k_hist_batch<<<(NN + 255) / 256, 256, 0, stream>>>(batch, gcnt);
  k_scan<<<1, 1024, 0, stream>>>(offs, cursor);
  k_fill<<<NE / 256, 256, 0, stream>>>(ei, ew, cursor, csr_src, csr_w);
  k_prep<<<512, 256, 0, stream>>>(conv_w, btp);

  // T_1 = A x
  k_spmv<<<(NN * 32) / 256, 256, 0, stream>>>(x, nullptr, rotA, tstore, offs, csr_src, csr_w, 1);
  const float* gat = rotA;  // holds T_{d-1}
  float* outb = rotB;       // destination (holds T_{d-2} for d>=3)
  const float* sub = x;     // T_{d-2}
  for (int d = 2; d <= DMAX; ++d) {
    k_spmv<<<(NN * 32) / 256, 256, 0, stream>>>(gat, sub, outb,
        tstore + (size_t)(d - 1) * SLICE, offs, csr_src, csr_w, 0);
    const float* ng = outb;
    outb = (float*)gat;
    sub = gat;
    gat = ng;
  }

  k_acc<<<(NN * 64) / 256, 256, 0, stream>>>(x, tstore, coefs, accb);
  k_conv<<<(NN + 63) / 64, 256, 0, stream>>>(accb, btp, conv_b, batch, gsums);
  k_final<<<NG, 256, 0, stream>>>(gsums, gcnt, fc_w, fc_b, out);
}